// Round 1
// baseline (991.952 us; speedup 1.0000x reference)
//
#include <hip/hip_runtime.h>

// ---------------------------------------------------------------------------
// GCN 3-layer forward. fp32 throughout (error threshold 7.6e-4 forbids bf16).
// Strategy: CSR build per call (no cross-call state), gather-based aggregation
// (no scatter atomics in steady state), fused epilogue (self-loop+bias+relu).
// ---------------------------------------------------------------------------

__global__ __launch_bounds__(256)
void deg_kernel(const int* __restrict__ dst, int* __restrict__ cnt, int E) {
  int e = blockIdx.x * 256 + threadIdx.x;
  if (e < E) atomicAdd(&cnt[dst[e]], 1);
}

__global__ __launch_bounds__(256)
void dinv_kernel(const int* __restrict__ cnt, float* __restrict__ dinv, int n) {
  int i = blockIdx.x * 256 + threadIdx.x;
  if (i < n) dinv[i] = 1.0f / sqrtf((float)cnt[i] + 1.0f);
}

// Single-block blocked Hillis-Steele scan over degree counts -> rowptr, woff.
__global__ __launch_bounds__(1024)
void scan_kernel(const int* __restrict__ cnt, int* __restrict__ rowptr,
                 int* __restrict__ woff, int n) {
  __shared__ int sm[1024];
  int tid = threadIdx.x;
  int chunk = (n + 1023) >> 10;
  int begin = min(tid * chunk, n);
  int end = min(begin + chunk, n);
  int s = 0;
  for (int i = begin; i < end; ++i) s += cnt[i];
  sm[tid] = s;
  __syncthreads();
  for (int off = 1; off < 1024; off <<= 1) {
    int v = 0;
    if (tid >= off) v = sm[tid - off];
    __syncthreads();
    sm[tid] += v;
    __syncthreads();
  }
  int prefix = tid ? sm[tid - 1] : 0;
  for (int i = begin; i < end; ++i) {
    rowptr[i] = prefix;
    woff[i] = prefix;
    prefix += cnt[i];
  }
  if (tid == 1023) rowptr[n] = sm[1023];
}

__global__ __launch_bounds__(256)
void fill_kernel(const int* __restrict__ src, const int* __restrict__ dst,
                 int* __restrict__ woff, int* __restrict__ col, int E) {
  int e = blockIdx.x * 256 + threadIdx.x;
  if (e < E) {
    int d = dst[e];
    int pos = atomicAdd(&woff[d], 1);
    col[pos] = src[e];
  }
}

// G[r][c] = dinv[r] * sum_k X[r][k] * W[k][c].  K=128 fixed. fp32 vector ALU.
// 256 threads; micro-tile TM x TN per thread; BK=32 LDS-staged.
template <int M, int BM, int TM, int TN>
__global__ __launch_bounds__(256)
void gemm_scale_kernel(const float* __restrict__ X, const float* __restrict__ W,
                       const float* __restrict__ dinv, float* __restrict__ G,
                       int nrows) {
  constexpr int BK = 32;
  constexpr int GCOL = M / TN;  // column groups
  static_assert((256 / GCOL) * TM == BM, "tile shape");
  __shared__ float xs[BM][BK + 1];   // +1 pad: kill power-of-2 bank stride
  __shared__ float wsh[BK][M];

  int tid = threadIdx.x;
  int row0 = blockIdx.x * BM;
  int tx = tid % GCOL;
  int ty = tid / GCOL;
  int r0 = ty * TM;
  int c0 = tx * TN;

  float acc[TM][TN];
#pragma unroll
  for (int i = 0; i < TM; ++i)
#pragma unroll
    for (int j = 0; j < TN; ++j) acc[i][j] = 0.0f;

  for (int k0 = 0; k0 < 128; k0 += BK) {
    // stage X tile (BM x BK) via float4, coalesced over k
#pragma unroll
    for (int t = tid; t < BM * (BK / 4); t += 256) {
      int r = t / (BK / 4);
      int kk = (t % (BK / 4)) * 4;
      int grow = row0 + r;
      float4 v = make_float4(0.f, 0.f, 0.f, 0.f);
      if (grow < nrows)
        v = *(const float4*)(X + (size_t)grow * 128 + k0 + kk);
      xs[r][kk] = v.x;
      xs[r][kk + 1] = v.y;
      xs[r][kk + 2] = v.z;
      xs[r][kk + 3] = v.w;
    }
    // stage W tile (BK x M) via float4 (M % 4 == 0)
#pragma unroll
    for (int t = tid; t < BK * M / 4; t += 256) {
      int k = (t * 4) / M;
      int c = (t * 4) % M;
      *(float4*)(&wsh[k][c]) = *(const float4*)(W + (size_t)(k0 + k) * M + c);
    }
    __syncthreads();
#pragma unroll 4
    for (int k = 0; k < BK; ++k) {
      float a[TM], b[TN];
#pragma unroll
      for (int i = 0; i < TM; ++i) a[i] = xs[r0 + i][k];
#pragma unroll
      for (int j = 0; j < TN; ++j) b[j] = wsh[k][c0 + j];
#pragma unroll
      for (int i = 0; i < TM; ++i)
#pragma unroll
        for (int j = 0; j < TN; ++j) acc[i][j] += a[i] * b[j];
    }
    __syncthreads();
  }
#pragma unroll
  for (int i = 0; i < TM; ++i) {
    int grow = row0 + r0 + i;
    if (grow < nrows) {
      float s = dinv[grow];
#pragma unroll
      for (int j = 0; j < TN; ++j)
        G[(size_t)grow * M + c0 + j] = s * acc[i][j];
    }
  }
}

// out[i][:] = act( dinv[i] * (sum_{e in CSR row i} G[col[e]][:] + G[i][:]) + b )
// One wave per node. M=128: float2/lane. M=40: lanes 0..39 scalar.
template <int M, bool RELU>
__global__ __launch_bounds__(256)
void aggregate_kernel(const float* __restrict__ G, const int* __restrict__ rowptr,
                      const int* __restrict__ col, const float* __restrict__ dinv,
                      const float* __restrict__ bias, float* __restrict__ out,
                      int n) {
  int wid = threadIdx.x >> 6;
  int lane = threadIdx.x & 63;
  int node = blockIdx.x * 4 + wid;
  if (node >= n) return;

  int e = rowptr[node];
  int end = rowptr[node + 1];
  float di = dinv[node];

  if constexpr (M == 128) {
    const float2* g2 = (const float2*)G;
    float2 acc = g2[(size_t)node * 64 + lane];  // self-loop term g[i]
    // unroll-by-2: two outstanding gathers
    for (; e + 1 < end; e += 2) {
      int s0 = col[e];
      int s1 = col[e + 1];
      float2 v0 = g2[(size_t)s0 * 64 + lane];
      float2 v1 = g2[(size_t)s1 * 64 + lane];
      acc.x += v0.x + v1.x;
      acc.y += v0.y + v1.y;
    }
    if (e < end) {
      int s0 = col[e];
      float2 v0 = g2[(size_t)s0 * 64 + lane];
      acc.x += v0.x;
      acc.y += v0.y;
    }
    float2 bb = ((const float2*)bias)[lane];
    float ox = di * acc.x + bb.x;
    float oy = di * acc.y + bb.y;
    if (RELU) {
      ox = fmaxf(ox, 0.0f);
      oy = fmaxf(oy, 0.0f);
    }
    ((float2*)out)[(size_t)node * 64 + lane] = make_float2(ox, oy);
  } else {
    if (lane < M) {
      float acc = G[(size_t)node * M + lane];
      for (; e + 1 < end; e += 2) {
        int s0 = col[e];
        int s1 = col[e + 1];
        acc += G[(size_t)s0 * M + lane] + G[(size_t)s1 * M + lane];
      }
      if (e < end) acc += G[(size_t)col[e] * M + lane];
      float o = di * acc + bias[lane];
      if (RELU) o = fmaxf(o, 0.0f);
      out[(size_t)node * M + lane] = o;
    }
  }
}

extern "C" void kernel_launch(void* const* d_in, const int* in_sizes, int n_in,
                              void* d_out, int out_size, void* d_ws, size_t ws_size,
                              hipStream_t stream) {
  const float* x = (const float*)d_in[0];
  const float* W0 = (const float*)d_in[1];
  const float* b0 = (const float*)d_in[2];
  const float* W1 = (const float*)d_in[3];
  const float* b1 = (const float*)d_in[4];
  const float* W2 = (const float*)d_in[5];
  const float* b2 = (const float*)d_in[6];
  const int* ei = (const int*)d_in[7];

  const int N = in_sizes[0] / 128;
  const int E = in_sizes[7] / 2;
  const int* src = ei;
  const int* dst = ei + E;

  // workspace bump allocator, 256B aligned
  char* w = (char*)d_ws;
  size_t off = 0;
  auto alloc = [&](size_t bytes) -> void* {
    void* p = w + off;
    off = (off + bytes + 255) & ~(size_t)255;
    return p;
  };
  int* cnt = (int*)alloc((size_t)N * 4);
  float* dinv = (float*)alloc((size_t)N * 4);
  int* rowptr = (int*)alloc((size_t)(N + 1) * 4);
  int* woff = (int*)alloc((size_t)N * 4);
  int* col = (int*)alloc((size_t)E * 4);
  float* bufA = (float*)alloc((size_t)N * 128 * 4);
  float* bufB = (float*)alloc((size_t)N * 128 * 4);
  (void)ws_size;

  hipMemsetAsync(cnt, 0, (size_t)N * 4, stream);

  dim3 blk(256);
  int gE = (E + 255) / 256;
  int gN = (N + 255) / 256;

  deg_kernel<<<gE, blk, 0, stream>>>(dst, cnt, E);
  dinv_kernel<<<gN, blk, 0, stream>>>(cnt, dinv, N);
  scan_kernel<<<1, 1024, 0, stream>>>(cnt, rowptr, woff, N);
  fill_kernel<<<gE, blk, 0, stream>>>(src, dst, woff, col, E);

  int gGemm128 = (N + 63) / 64;
  int gGemm40 = (N + 127) / 128;
  int gAgg = (N + 3) / 4;

  // layer 0: x -> bufA (g0), aggregate -> bufB (h1, relu)
  gemm_scale_kernel<128, 64, 8, 4><<<gGemm128, blk, 0, stream>>>(x, W0, dinv, bufA, N);
  aggregate_kernel<128, true><<<gAgg, blk, 0, stream>>>(bufA, rowptr, col, dinv, b0, bufB, N);
  // layer 1: bufB -> bufA (g1), aggregate -> bufB (h2, relu)
  gemm_scale_kernel<128, 64, 8, 4><<<gGemm128, blk, 0, stream>>>(bufB, W1, dinv, bufA, N);
  aggregate_kernel<128, true><<<gAgg, blk, 0, stream>>>(bufA, rowptr, col, dinv, b1, bufB, N);
  // layer 2: bufB -> bufA (g2, 40 cols), aggregate -> d_out (no relu)
  gemm_scale_kernel<40, 128, 4, 5><<<gGemm40, blk, 0, stream>>>(bufB, W2, dinv, bufA, N);
  aggregate_kernel<40, false><<<gAgg, blk, 0, stream>>>(bufA, rowptr, col, dinv, b2,
                                                        (float*)d_out, N);
}

// Round 2
// 768.817 us; speedup vs baseline: 1.2902x; 1.2902x over previous
//
#include <hip/hip_runtime.h>

// ---------------------------------------------------------------------------
// GCN 3-layer forward. fp32 throughout (error threshold 7.6e-4 forbids bf16).
// Strategy: CSR build per call (no cross-call state), gather-based aggregation
// (no scatter atomics in steady state), fused epilogue (self-loop+bias+relu).
// R1: single-block scan was 233us (23% of total, 1 CU). -> 3-phase multi-block
// scan, each phase launch-bound.
// ---------------------------------------------------------------------------

__global__ __launch_bounds__(256)
void deg_kernel(const int* __restrict__ dst, int* __restrict__ cnt, int E) {
  int e = blockIdx.x * 256 + threadIdx.x;
  if (e < E) atomicAdd(&cnt[dst[e]], 1);
}

__global__ __launch_bounds__(256)
void dinv_kernel(const int* __restrict__ cnt, float* __restrict__ dinv, int n) {
  int i = blockIdx.x * 256 + threadIdx.x;
  if (i < n) dinv[i] = 1.0f / sqrtf((float)cnt[i] + 1.0f);
}

// ---- 3-phase exclusive scan over cnt[0..n) -> rowptr/woff ----
// Phase 1: per-block (2048 elems) total via LDS tree reduce.
__global__ __launch_bounds__(256)
void scan_partial_kernel(const int* __restrict__ cnt, int* __restrict__ blocksums,
                         int n) {
  __shared__ int sm[256];
  int base = blockIdx.x * 2048 + threadIdx.x * 8;
  int s = 0;
#pragma unroll
  for (int i = 0; i < 8; ++i) {
    int idx = base + i;
    if (idx < n) s += cnt[idx];
  }
  sm[threadIdx.x] = s;
  __syncthreads();
#pragma unroll
  for (int off = 128; off > 0; off >>= 1) {
    if (threadIdx.x < off) sm[threadIdx.x] += sm[threadIdx.x + off];
    __syncthreads();
  }
  if (threadIdx.x == 0) blocksums[blockIdx.x] = sm[0];
}

// Phase 2: serial exclusive scan of blocksums (nb ~ 49; launch-bound anyway).
__global__ void scan_blocksums_kernel(int* __restrict__ blocksums, int nb) {
  if (threadIdx.x == 0 && blockIdx.x == 0) {
    int run = 0;
    for (int i = 0; i < nb; ++i) {
      int v = blocksums[i];
      blocksums[i] = run;
      run += v;
    }
  }
}

// Phase 3: intra-block exclusive scan + block offset -> rowptr, woff.
__global__ __launch_bounds__(256)
void scan_write_kernel(const int* __restrict__ cnt, const int* __restrict__ blockoff,
                       int* __restrict__ rowptr, int* __restrict__ woff,
                       int n, int E) {
  __shared__ int sm[256];
  int t = threadIdx.x;
  int base = blockIdx.x * 2048 + t * 8;
  int v[8];
  int s = 0;
#pragma unroll
  for (int i = 0; i < 8; ++i) {
    int idx = base + i;
    v[i] = (idx < n) ? cnt[idx] : 0;
    s += v[i];
  }
  sm[t] = s;
  __syncthreads();
  // inclusive Hillis-Steele over 256 per-thread sums
#pragma unroll
  for (int off = 1; off < 256; off <<= 1) {
    int u = (t >= off) ? sm[t - off] : 0;
    __syncthreads();
    sm[t] += u;
    __syncthreads();
  }
  int p = blockoff[blockIdx.x] + (t ? sm[t - 1] : 0);
#pragma unroll
  for (int i = 0; i < 8; ++i) {
    int idx = base + i;
    if (idx < n) {
      rowptr[idx] = p;
      woff[idx] = p;
      p += v[i];
    }
  }
  if (blockIdx.x == 0 && t == 0) rowptr[n] = E;
}

__global__ __launch_bounds__(256)
void fill_kernel(const int* __restrict__ src, const int* __restrict__ dst,
                 int* __restrict__ woff, int* __restrict__ col, int E) {
  int e = blockIdx.x * 256 + threadIdx.x;
  if (e < E) {
    int d = dst[e];
    int pos = atomicAdd(&woff[d], 1);
    col[pos] = src[e];
  }
}

// G[r][c] = dinv[r] * sum_k X[r][k] * W[k][c].  K=128 fixed. fp32 vector ALU.
template <int M, int BM, int TM, int TN>
__global__ __launch_bounds__(256)
void gemm_scale_kernel(const float* __restrict__ X, const float* __restrict__ W,
                       const float* __restrict__ dinv, float* __restrict__ G,
                       int nrows) {
  constexpr int BK = 32;
  constexpr int GCOL = M / TN;  // column groups
  static_assert((256 / GCOL) * TM == BM, "tile shape");
  __shared__ float xs[BM][BK + 1];   // +1 pad: kill power-of-2 bank stride
  __shared__ float wsh[BK][M];

  int tid = threadIdx.x;
  int row0 = blockIdx.x * BM;
  int tx = tid % GCOL;
  int ty = tid / GCOL;
  int r0 = ty * TM;
  int c0 = tx * TN;

  float acc[TM][TN];
#pragma unroll
  for (int i = 0; i < TM; ++i)
#pragma unroll
    for (int j = 0; j < TN; ++j) acc[i][j] = 0.0f;

  for (int k0 = 0; k0 < 128; k0 += BK) {
#pragma unroll
    for (int t = tid; t < BM * (BK / 4); t += 256) {
      int r = t / (BK / 4);
      int kk = (t % (BK / 4)) * 4;
      int grow = row0 + r;
      float4 v = make_float4(0.f, 0.f, 0.f, 0.f);
      if (grow < nrows)
        v = *(const float4*)(X + (size_t)grow * 128 + k0 + kk);
      xs[r][kk] = v.x;
      xs[r][kk + 1] = v.y;
      xs[r][kk + 2] = v.z;
      xs[r][kk + 3] = v.w;
    }
#pragma unroll
    for (int t = tid; t < BK * M / 4; t += 256) {
      int k = (t * 4) / M;
      int c = (t * 4) % M;
      *(float4*)(&wsh[k][c]) = *(const float4*)(W + (size_t)(k0 + k) * M + c);
    }
    __syncthreads();
#pragma unroll 4
    for (int k = 0; k < BK; ++k) {
      float a[TM], b[TN];
#pragma unroll
      for (int i = 0; i < TM; ++i) a[i] = xs[r0 + i][k];
#pragma unroll
      for (int j = 0; j < TN; ++j) b[j] = wsh[k][c0 + j];
#pragma unroll
      for (int i = 0; i < TM; ++i)
#pragma unroll
        for (int j = 0; j < TN; ++j) acc[i][j] += a[i] * b[j];
    }
    __syncthreads();
  }
#pragma unroll
  for (int i = 0; i < TM; ++i) {
    int grow = row0 + r0 + i;
    if (grow < nrows) {
      float s = dinv[grow];
#pragma unroll
      for (int j = 0; j < TN; ++j)
        G[(size_t)grow * M + c0 + j] = s * acc[i][j];
    }
  }
}

// out[i][:] = act( dinv[i] * (sum_{e in CSR row i} G[col[e]][:] + G[i][:]) + b )
// One wave per node. M=128: float2/lane. M=40: lanes 0..39 scalar.
template <int M, bool RELU>
__global__ __launch_bounds__(256)
void aggregate_kernel(const float* __restrict__ G, const int* __restrict__ rowptr,
                      const int* __restrict__ col, const float* __restrict__ dinv,
                      const float* __restrict__ bias, float* __restrict__ out,
                      int n) {
  int wid = threadIdx.x >> 6;
  int lane = threadIdx.x & 63;
  int node = blockIdx.x * 4 + wid;
  if (node >= n) return;

  int e = rowptr[node];
  int end = rowptr[node + 1];
  float di = dinv[node];

  if constexpr (M == 128) {
    const float2* g2 = (const float2*)G;
    float2 acc = g2[(size_t)node * 64 + lane];  // self-loop term g[i]
    for (; e + 1 < end; e += 2) {
      int s0 = col[e];
      int s1 = col[e + 1];
      float2 v0 = g2[(size_t)s0 * 64 + lane];
      float2 v1 = g2[(size_t)s1 * 64 + lane];
      acc.x += v0.x + v1.x;
      acc.y += v0.y + v1.y;
    }
    if (e < end) {
      int s0 = col[e];
      float2 v0 = g2[(size_t)s0 * 64 + lane];
      acc.x += v0.x;
      acc.y += v0.y;
    }
    float2 bb = ((const float2*)bias)[lane];
    float ox = di * acc.x + bb.x;
    float oy = di * acc.y + bb.y;
    if (RELU) {
      ox = fmaxf(ox, 0.0f);
      oy = fmaxf(oy, 0.0f);
    }
    ((float2*)out)[(size_t)node * 64 + lane] = make_float2(ox, oy);
  } else {
    if (lane < M) {
      float acc = G[(size_t)node * M + lane];
      for (; e + 1 < end; e += 2) {
        int s0 = col[e];
        int s1 = col[e + 1];
        acc += G[(size_t)s0 * M + lane] + G[(size_t)s1 * M + lane];
      }
      if (e < end) acc += G[(size_t)col[e] * M + lane];
      float o = di * acc + bias[lane];
      if (RELU) o = fmaxf(o, 0.0f);
      out[(size_t)node * M + lane] = o;
    }
  }
}

extern "C" void kernel_launch(void* const* d_in, const int* in_sizes, int n_in,
                              void* d_out, int out_size, void* d_ws, size_t ws_size,
                              hipStream_t stream) {
  const float* x = (const float*)d_in[0];
  const float* W0 = (const float*)d_in[1];
  const float* b0 = (const float*)d_in[2];
  const float* W1 = (const float*)d_in[3];
  const float* b1 = (const float*)d_in[4];
  const float* W2 = (const float*)d_in[5];
  const float* b2 = (const float*)d_in[6];
  const int* ei = (const int*)d_in[7];

  const int N = in_sizes[0] / 128;
  const int E = in_sizes[7] / 2;
  const int* src = ei;
  const int* dst = ei + E;

  char* w = (char*)d_ws;
  size_t off = 0;
  auto alloc = [&](size_t bytes) -> void* {
    void* p = w + off;
    off = (off + bytes + 255) & ~(size_t)255;
    return p;
  };
  int* cnt = (int*)alloc((size_t)N * 4);
  float* dinv = (float*)alloc((size_t)N * 4);
  int* rowptr = (int*)alloc((size_t)(N + 1) * 4);
  int* woff = (int*)alloc((size_t)N * 4);
  int* col = (int*)alloc((size_t)E * 4);
  int* blocksums = (int*)alloc(4096 * 4);
  float* bufA = (float*)alloc((size_t)N * 128 * 4);
  float* bufB = (float*)alloc((size_t)N * 128 * 4);
  (void)ws_size;

  hipMemsetAsync(cnt, 0, (size_t)N * 4, stream);

  dim3 blk(256);
  int gE = (E + 255) / 256;
  int gN = (N + 255) / 256;
  int nScanBlocks = (N + 2047) / 2048;

  deg_kernel<<<gE, blk, 0, stream>>>(dst, cnt, E);
  dinv_kernel<<<gN, blk, 0, stream>>>(cnt, dinv, N);
  scan_partial_kernel<<<nScanBlocks, blk, 0, stream>>>(cnt, blocksums, N);
  scan_blocksums_kernel<<<1, 64, 0, stream>>>(blocksums, nScanBlocks);
  scan_write_kernel<<<nScanBlocks, blk, 0, stream>>>(cnt, blocksums, rowptr, woff, N, E);
  fill_kernel<<<gE, blk, 0, stream>>>(src, dst, woff, col, E);

  int gGemm128 = (N + 63) / 64;
  int gGemm40 = (N + 127) / 128;
  int gAgg = (N + 3) / 4;

  gemm_scale_kernel<128, 64, 8, 4><<<gGemm128, blk, 0, stream>>>(x, W0, dinv, bufA, N);
  aggregate_kernel<128, true><<<gAgg, blk, 0, stream>>>(bufA, rowptr, col, dinv, b0, bufB, N);
  gemm_scale_kernel<128, 64, 8, 4><<<gGemm128, blk, 0, stream>>>(bufB, W1, dinv, bufA, N);
  aggregate_kernel<128, true><<<gAgg, blk, 0, stream>>>(bufA, rowptr, col, dinv, b1, bufB, N);
  gemm_scale_kernel<40, 128, 4, 5><<<gGemm40, blk, 0, stream>>>(bufB, W2, dinv, bufA, N);
  aggregate_kernel<40, false><<<gAgg, blk, 0, stream>>>(bufA, rowptr, col, dinv, b2,
                                                        (float*)d_out, N);
}

// Round 3
// 750.204 us; speedup vs baseline: 1.3222x; 1.0248x over previous
//
#include <hip/hip_runtime.h>

// ---------------------------------------------------------------------------
// GCN 3-layer forward. fp32 throughout (error threshold 7.6e-4 forbids bf16).
// CSR build per call; gather-based aggregation; fused epilogue.
// R1: multi-block scan (was 233us single-block).
// R2->R3: fill phase-split by dst range (write-amp 16x -> ~7x: scatter window
//         L2-resident per phase); gemm128 with transposed X tile so A and B
//         fragments both load as ds_read_b128; float4 epilogue.
// ---------------------------------------------------------------------------

__global__ __launch_bounds__(256)
void deg_kernel(const int* __restrict__ dst, int* __restrict__ cnt, int E) {
  int e = blockIdx.x * 256 + threadIdx.x;
  if (e < E) atomicAdd(&cnt[dst[e]], 1);
}

__global__ __launch_bounds__(256)
void dinv_kernel(const int* __restrict__ cnt, float* __restrict__ dinv, int n) {
  int i = blockIdx.x * 256 + threadIdx.x;
  if (i < n) dinv[i] = 1.0f / sqrtf((float)cnt[i] + 1.0f);
}

// ---- 3-phase exclusive scan over cnt[0..n) -> rowptr/woff ----
__global__ __launch_bounds__(256)
void scan_partial_kernel(const int* __restrict__ cnt, int* __restrict__ blocksums,
                         int n) {
  __shared__ int sm[256];
  int base = blockIdx.x * 2048 + threadIdx.x * 8;
  int s = 0;
#pragma unroll
  for (int i = 0; i < 8; ++i) {
    int idx = base + i;
    if (idx < n) s += cnt[idx];
  }
  sm[threadIdx.x] = s;
  __syncthreads();
#pragma unroll
  for (int off = 128; off > 0; off >>= 1) {
    if (threadIdx.x < off) sm[threadIdx.x] += sm[threadIdx.x + off];
    __syncthreads();
  }
  if (threadIdx.x == 0) blocksums[blockIdx.x] = sm[0];
}

__global__ void scan_blocksums_kernel(int* __restrict__ blocksums, int nb) {
  if (threadIdx.x == 0 && blockIdx.x == 0) {
    int run = 0;
    for (int i = 0; i < nb; ++i) {
      int v = blocksums[i];
      blocksums[i] = run;
      run += v;
    }
  }
}

__global__ __launch_bounds__(256)
void scan_write_kernel(const int* __restrict__ cnt, const int* __restrict__ blockoff,
                       int* __restrict__ rowptr, int* __restrict__ woff,
                       int n, int E) {
  __shared__ int sm[256];
  int t = threadIdx.x;
  int base = blockIdx.x * 2048 + t * 8;
  int v[8];
  int s = 0;
#pragma unroll
  for (int i = 0; i < 8; ++i) {
    int idx = base + i;
    v[i] = (idx < n) ? cnt[idx] : 0;
    s += v[i];
  }
  sm[t] = s;
  __syncthreads();
#pragma unroll
  for (int off = 1; off < 256; off <<= 1) {
    int u = (t >= off) ? sm[t - off] : 0;
    __syncthreads();
    sm[t] += u;
    __syncthreads();
  }
  int p = blockoff[blockIdx.x] + (t ? sm[t - 1] : 0);
#pragma unroll
  for (int i = 0; i < 8; ++i) {
    int idx = base + i;
    if (idx < n) {
      rowptr[idx] = p;
      woff[idx] = p;
      p += v[i];
    }
  }
  if (blockIdx.x == 0 && t == 0) rowptr[n] = E;
}

// Phase-filtered counting-sort scatter: only edges with dst in [lo,hi) write.
// Keeps the active col window (~E/P entries ~1.6MB) L2-resident so same-XCD
// 4B stores merge before writeback (R2: 105MB write traffic for 6.4MB col).
__global__ __launch_bounds__(256)
void fill_phase_kernel(const int* __restrict__ src, const int* __restrict__ dst,
                       int* __restrict__ woff, int* __restrict__ col, int E,
                       int lo, int hi) {
  int e = blockIdx.x * 256 + threadIdx.x;
  if (e < E) {
    int d = dst[e];
    if (d >= lo && d < hi) {
      int pos = atomicAdd(&woff[d], 1);
      col[pos] = src[e];
    }
  }
}

// G[r][c] = dinv[r] * sum_k X[r][k] * W[k][c]. M=128, K=128. fp32 vector ALU.
// X tile stored transposed in LDS -> both A and B fragments are ds_read_b128.
__global__ __launch_bounds__(256)
void gemm128_kernel(const float* __restrict__ X, const float* __restrict__ W,
                    const float* __restrict__ dinv, float* __restrict__ G,
                    int nrows) {
  constexpr int BM = 64, BK = 32, TM = 8, TN = 4;
  __shared__ float xs[BK][BM + 4];   // +4: keeps 16B alignment, breaks pow2 stride
  __shared__ float wsh[BK][128];

  int tid = threadIdx.x;
  int row0 = blockIdx.x * BM;
  int tx = tid & 31;         // 32 column groups of TN=4
  int ty = tid >> 5;         // 8 row groups of TM=8
  int r0 = ty * TM;
  int c0 = tx * TN;

  float acc[TM][TN];
#pragma unroll
  for (int i = 0; i < TM; ++i)
#pragma unroll
    for (int j = 0; j < TN; ++j) acc[i][j] = 0.0f;

  for (int k0 = 0; k0 < 128; k0 += BK) {
    // stage X (BM x BK) transposed: thread reads float4 along k, scatters to 4 rows
#pragma unroll
    for (int t = tid; t < BM * (BK / 4); t += 256) {
      int r = t >> 3;
      int kk = (t & 7) * 4;
      int grow = row0 + r;
      float4 v = make_float4(0.f, 0.f, 0.f, 0.f);
      if (grow < nrows)
        v = *(const float4*)(X + (size_t)grow * 128 + k0 + kk);
      xs[kk + 0][r] = v.x;
      xs[kk + 1][r] = v.y;
      xs[kk + 2][r] = v.z;
      xs[kk + 3][r] = v.w;
    }
    // stage W (BK x 128) via float4
#pragma unroll
    for (int t = tid; t < BK * 32; t += 256) {
      int k = t >> 5;
      int c = (t & 31) * 4;
      *(float4*)(&wsh[k][c]) = *(const float4*)(W + (size_t)(k0 + k) * 128 + c);
    }
    __syncthreads();
#pragma unroll 8
    for (int k = 0; k < BK; ++k) {
      float4 a0 = *(const float4*)(&xs[k][r0]);
      float4 a1 = *(const float4*)(&xs[k][r0 + 4]);
      float4 b = *(const float4*)(&wsh[k][c0]);
      float a[TM] = {a0.x, a0.y, a0.z, a0.w, a1.x, a1.y, a1.z, a1.w};
      float bb[TN] = {b.x, b.y, b.z, b.w};
#pragma unroll
      for (int i = 0; i < TM; ++i)
#pragma unroll
        for (int j = 0; j < TN; ++j) acc[i][j] += a[i] * bb[j];
    }
    __syncthreads();
  }
#pragma unroll
  for (int i = 0; i < TM; ++i) {
    int grow = row0 + r0 + i;
    if (grow < nrows) {
      float s = dinv[grow];
      float4 o = make_float4(s * acc[i][0], s * acc[i][1], s * acc[i][2],
                             s * acc[i][3]);
      *(float4*)(G + (size_t)grow * 128 + c0) = o;
    }
  }
}

// Generic (used for M=40 output layer). Scalar LDS reads, fine for small M.
template <int M, int BM, int TM, int TN>
__global__ __launch_bounds__(256)
void gemm_scale_kernel(const float* __restrict__ X, const float* __restrict__ W,
                       const float* __restrict__ dinv, float* __restrict__ G,
                       int nrows) {
  constexpr int BK = 32;
  constexpr int GCOL = M / TN;
  static_assert((256 / GCOL) * TM == BM, "tile shape");
  __shared__ float xs[BM][BK + 1];
  __shared__ float wsh[BK][M];

  int tid = threadIdx.x;
  int row0 = blockIdx.x * BM;
  int tx = tid % GCOL;
  int ty = tid / GCOL;
  int r0 = ty * TM;
  int c0 = tx * TN;

  float acc[TM][TN];
#pragma unroll
  for (int i = 0; i < TM; ++i)
#pragma unroll
    for (int j = 0; j < TN; ++j) acc[i][j] = 0.0f;

  for (int k0 = 0; k0 < 128; k0 += BK) {
#pragma unroll
    for (int t = tid; t < BM * (BK / 4); t += 256) {
      int r = t / (BK / 4);
      int kk = (t % (BK / 4)) * 4;
      int grow = row0 + r;
      float4 v = make_float4(0.f, 0.f, 0.f, 0.f);
      if (grow < nrows)
        v = *(const float4*)(X + (size_t)grow * 128 + k0 + kk);
      xs[r][kk] = v.x;
      xs[r][kk + 1] = v.y;
      xs[r][kk + 2] = v.z;
      xs[r][kk + 3] = v.w;
    }
#pragma unroll
    for (int t = tid; t < BK * M / 4; t += 256) {
      int k = (t * 4) / M;
      int c = (t * 4) % M;
      *(float4*)(&wsh[k][c]) = *(const float4*)(W + (size_t)(k0 + k) * M + c);
    }
    __syncthreads();
#pragma unroll 4
    for (int k = 0; k < BK; ++k) {
      float a[TM], b[TN];
#pragma unroll
      for (int i = 0; i < TM; ++i) a[i] = xs[r0 + i][k];
#pragma unroll
      for (int j = 0; j < TN; ++j) b[j] = wsh[k][c0 + j];
#pragma unroll
      for (int i = 0; i < TM; ++i)
#pragma unroll
        for (int j = 0; j < TN; ++j) acc[i][j] += a[i] * b[j];
    }
    __syncthreads();
  }
#pragma unroll
  for (int i = 0; i < TM; ++i) {
    int grow = row0 + r0 + i;
    if (grow < nrows) {
      float s = dinv[grow];
#pragma unroll
      for (int j = 0; j < TN; ++j)
        G[(size_t)grow * M + c0 + j] = s * acc[i][j];
    }
  }
}

// out[i][:] = act( dinv[i] * (sum_{e in row i} G[col[e]][:] + G[i][:]) + b )
template <int M, bool RELU>
__global__ __launch_bounds__(256)
void aggregate_kernel(const float* __restrict__ G, const int* __restrict__ rowptr,
                      const int* __restrict__ col, const float* __restrict__ dinv,
                      const float* __restrict__ bias, float* __restrict__ out,
                      int n) {
  int wid = threadIdx.x >> 6;
  int lane = threadIdx.x & 63;
  int node = blockIdx.x * 4 + wid;
  if (node >= n) return;

  int e = rowptr[node];
  int end = rowptr[node + 1];
  float di = dinv[node];

  if constexpr (M == 128) {
    const float2* g2 = (const float2*)G;
    float2 acc = g2[(size_t)node * 64 + lane];
    for (; e + 1 < end; e += 2) {
      int s0 = col[e];
      int s1 = col[e + 1];
      float2 v0 = g2[(size_t)s0 * 64 + lane];
      float2 v1 = g2[(size_t)s1 * 64 + lane];
      acc.x += v0.x + v1.x;
      acc.y += v0.y + v1.y;
    }
    if (e < end) {
      int s0 = col[e];
      float2 v0 = g2[(size_t)s0 * 64 + lane];
      acc.x += v0.x;
      acc.y += v0.y;
    }
    float2 bb = ((const float2*)bias)[lane];
    float ox = di * acc.x + bb.x;
    float oy = di * acc.y + bb.y;
    if (RELU) {
      ox = fmaxf(ox, 0.0f);
      oy = fmaxf(oy, 0.0f);
    }
    ((float2*)out)[(size_t)node * 64 + lane] = make_float2(ox, oy);
  } else {
    if (lane < M) {
      float acc = G[(size_t)node * M + lane];
      for (; e + 1 < end; e += 2) {
        int s0 = col[e];
        int s1 = col[e + 1];
        acc += G[(size_t)s0 * M + lane] + G[(size_t)s1 * M + lane];
      }
      if (e < end) acc += G[(size_t)col[e] * M + lane];
      float o = di * acc + bias[lane];
      if (RELU) o = fmaxf(o, 0.0f);
      out[(size_t)node * M + lane] = o;
    }
  }
}

extern "C" void kernel_launch(void* const* d_in, const int* in_sizes, int n_in,
                              void* d_out, int out_size, void* d_ws, size_t ws_size,
                              hipStream_t stream) {
  const float* x = (const float*)d_in[0];
  const float* W0 = (const float*)d_in[1];
  const float* b0 = (const float*)d_in[2];
  const float* W1 = (const float*)d_in[3];
  const float* b1 = (const float*)d_in[4];
  const float* W2 = (const float*)d_in[5];
  const float* b2 = (const float*)d_in[6];
  const int* ei = (const int*)d_in[7];

  const int N = in_sizes[0] / 128;
  const int E = in_sizes[7] / 2;
  const int* src = ei;
  const int* dst = ei + E;

  char* w = (char*)d_ws;
  size_t off = 0;
  auto alloc = [&](size_t bytes) -> void* {
    void* p = w + off;
    off = (off + bytes + 255) & ~(size_t)255;
    return p;
  };
  int* cnt = (int*)alloc((size_t)N * 4);
  float* dinv = (float*)alloc((size_t)N * 4);
  int* rowptr = (int*)alloc((size_t)(N + 1) * 4);
  int* woff = (int*)alloc((size_t)N * 4);
  int* col = (int*)alloc((size_t)E * 4);
  int* blocksums = (int*)alloc(4096 * 4);
  float* bufA = (float*)alloc((size_t)N * 128 * 4);
  float* bufB = (float*)alloc((size_t)N * 128 * 4);
  (void)ws_size;

  hipMemsetAsync(cnt, 0, (size_t)N * 4, stream);

  dim3 blk(256);
  int gE = (E + 255) / 256;
  int gN = (N + 255) / 256;
  int nScanBlocks = (N + 2047) / 2048;

  deg_kernel<<<gE, blk, 0, stream>>>(dst, cnt, E);
  dinv_kernel<<<gN, blk, 0, stream>>>(cnt, dinv, N);
  scan_partial_kernel<<<nScanBlocks, blk, 0, stream>>>(cnt, blocksums, N);
  scan_blocksums_kernel<<<1, 64, 0, stream>>>(blocksums, nScanBlocks);
  scan_write_kernel<<<nScanBlocks, blk, 0, stream>>>(cnt, blocksums, rowptr, woff, N, E);

  // Phase-split counting-sort scatter (P=4 dst ranges, each col window ~E/4*4B)
  const int P = 4;
  int chunk = (N + P - 1) / P;
  for (int p = 0; p < P; ++p) {
    int lo = p * chunk;
    int hi = min(N, lo + chunk);
    fill_phase_kernel<<<gE, blk, 0, stream>>>(src, dst, woff, col, E, lo, hi);
  }

  int gGemm128 = (N + 63) / 64;
  int gGemm40 = (N + 127) / 128;
  int gAgg = (N + 3) / 4;

  gemm128_kernel<<<gGemm128, blk, 0, stream>>>(x, W0, dinv, bufA, N);
  aggregate_kernel<128, true><<<gAgg, blk, 0, stream>>>(bufA, rowptr, col, dinv, b0, bufB, N);
  gemm128_kernel<<<gGemm128, blk, 0, stream>>>(bufB, W1, dinv, bufA, N);
  aggregate_kernel<128, true><<<gAgg, blk, 0, stream>>>(bufA, rowptr, col, dinv, b1, bufB, N);
  gemm_scale_kernel<40, 128, 4, 5><<<gGemm40, blk, 0, stream>>>(bufB, W2, dinv, bufA, N);
  aggregate_kernel<40, false><<<gAgg, blk, 0, stream>>>(bufA, rowptr, col, dinv, b2,
                                                        (float*)d_out, N);
}

// Round 4
// 614.052 us; speedup vs baseline: 1.6154x; 1.2217x over previous
//
#include <hip/hip_runtime.h>
#include <hip/hip_fp16.h>

// ---------------------------------------------------------------------------
// GCN 3-layer forward. fp32 accumulate; fp16 message buffer G (R4).
// CSR build per call; gather-based aggregation; fused epilogue.
// R1: multi-block scan (was 233us single-block).
// R3: fill phase-split by dst range; gemm128 ds_read_b128 both operands.
// R4: aggregate was HBM/L3-BW-bound (FETCH 402MB vs 819MB logical, 3.67TB/s).
//     G stored fp16 -> halves gather bytes; fp32 accumulation keeps absmax
//     ~2e-4 << 7.6e-4 threshold. Gather loop unroll x4.
// ---------------------------------------------------------------------------

__global__ __launch_bounds__(256)
void deg_kernel(const int* __restrict__ dst, int* __restrict__ cnt, int E) {
  int e = blockIdx.x * 256 + threadIdx.x;
  if (e < E) atomicAdd(&cnt[dst[e]], 1);
}

__global__ __launch_bounds__(256)
void dinv_kernel(const int* __restrict__ cnt, float* __restrict__ dinv, int n) {
  int i = blockIdx.x * 256 + threadIdx.x;
  if (i < n) dinv[i] = 1.0f / sqrtf((float)cnt[i] + 1.0f);
}

// ---- 3-phase exclusive scan over cnt[0..n) -> rowptr/woff ----
__global__ __launch_bounds__(256)
void scan_partial_kernel(const int* __restrict__ cnt, int* __restrict__ blocksums,
                         int n) {
  __shared__ int sm[256];
  int base = blockIdx.x * 2048 + threadIdx.x * 8;
  int s = 0;
#pragma unroll
  for (int i = 0; i < 8; ++i) {
    int idx = base + i;
    if (idx < n) s += cnt[idx];
  }
  sm[threadIdx.x] = s;
  __syncthreads();
#pragma unroll
  for (int off = 128; off > 0; off >>= 1) {
    if (threadIdx.x < off) sm[threadIdx.x] += sm[threadIdx.x + off];
    __syncthreads();
  }
  if (threadIdx.x == 0) blocksums[blockIdx.x] = sm[0];
}

__global__ void scan_blocksums_kernel(int* __restrict__ blocksums, int nb) {
  if (threadIdx.x == 0 && blockIdx.x == 0) {
    int run = 0;
    for (int i = 0; i < nb; ++i) {
      int v = blocksums[i];
      blocksums[i] = run;
      run += v;
    }
  }
}

__global__ __launch_bounds__(256)
void scan_write_kernel(const int* __restrict__ cnt, const int* __restrict__ blockoff,
                       int* __restrict__ rowptr, int* __restrict__ woff,
                       int n, int E) {
  __shared__ int sm[256];
  int t = threadIdx.x;
  int base = blockIdx.x * 2048 + t * 8;
  int v[8];
  int s = 0;
#pragma unroll
  for (int i = 0; i < 8; ++i) {
    int idx = base + i;
    v[i] = (idx < n) ? cnt[idx] : 0;
    s += v[i];
  }
  sm[t] = s;
  __syncthreads();
#pragma unroll
  for (int off = 1; off < 256; off <<= 1) {
    int u = (t >= off) ? sm[t - off] : 0;
    __syncthreads();
    sm[t] += u;
    __syncthreads();
  }
  int p = blockoff[blockIdx.x] + (t ? sm[t - 1] : 0);
#pragma unroll
  for (int i = 0; i < 8; ++i) {
    int idx = base + i;
    if (idx < n) {
      rowptr[idx] = p;
      woff[idx] = p;
      p += v[i];
    }
  }
  if (blockIdx.x == 0 && t == 0) rowptr[n] = E;
}

__global__ __launch_bounds__(256)
void fill_phase_kernel(const int* __restrict__ src, const int* __restrict__ dst,
                       int* __restrict__ woff, int* __restrict__ col, int E,
                       int lo, int hi) {
  int e = blockIdx.x * 256 + threadIdx.x;
  if (e < E) {
    int d = dst[e];
    if (d >= lo && d < hi) {
      int pos = atomicAdd(&woff[d], 1);
      col[pos] = src[e];
    }
  }
}

// G[r][c] = fp16( dinv[r] * sum_k X[r][k] * W[k][c] ). M=128, K=128.
__global__ __launch_bounds__(256)
void gemm128_kernel(const float* __restrict__ X, const float* __restrict__ W,
                    const float* __restrict__ dinv, __half* __restrict__ G,
                    int nrows) {
  constexpr int BM = 64, BK = 32, TM = 8, TN = 4;
  __shared__ float xs[BK][BM + 4];
  __shared__ float wsh[BK][128];

  int tid = threadIdx.x;
  int row0 = blockIdx.x * BM;
  int tx = tid & 31;
  int ty = tid >> 5;
  int r0 = ty * TM;
  int c0 = tx * TN;

  float acc[TM][TN];
#pragma unroll
  for (int i = 0; i < TM; ++i)
#pragma unroll
    for (int j = 0; j < TN; ++j) acc[i][j] = 0.0f;

  for (int k0 = 0; k0 < 128; k0 += BK) {
#pragma unroll
    for (int t = tid; t < BM * (BK / 4); t += 256) {
      int r = t >> 3;
      int kk = (t & 7) * 4;
      int grow = row0 + r;
      float4 v = make_float4(0.f, 0.f, 0.f, 0.f);
      if (grow < nrows)
        v = *(const float4*)(X + (size_t)grow * 128 + k0 + kk);
      xs[kk + 0][r] = v.x;
      xs[kk + 1][r] = v.y;
      xs[kk + 2][r] = v.z;
      xs[kk + 3][r] = v.w;
    }
#pragma unroll
    for (int t = tid; t < BK * 32; t += 256) {
      int k = t >> 5;
      int c = (t & 31) * 4;
      *(float4*)(&wsh[k][c]) = *(const float4*)(W + (size_t)(k0 + k) * 128 + c);
    }
    __syncthreads();
#pragma unroll 8
    for (int k = 0; k < BK; ++k) {
      float4 a0 = *(const float4*)(&xs[k][r0]);
      float4 a1 = *(const float4*)(&xs[k][r0 + 4]);
      float4 b = *(const float4*)(&wsh[k][c0]);
      float a[TM] = {a0.x, a0.y, a0.z, a0.w, a1.x, a1.y, a1.z, a1.w};
      float bb[TN] = {b.x, b.y, b.z, b.w};
#pragma unroll
      for (int i = 0; i < TM; ++i)
#pragma unroll
        for (int j = 0; j < TN; ++j) acc[i][j] += a[i] * bb[j];
    }
    __syncthreads();
  }
#pragma unroll
  for (int i = 0; i < TM; ++i) {
    int grow = row0 + r0 + i;
    if (grow < nrows) {
      float s = dinv[grow];
      __half2 p0 = __floats2half2_rn(s * acc[i][0], s * acc[i][1]);
      __half2 p1 = __floats2half2_rn(s * acc[i][2], s * acc[i][3]);
      __half2* gp = (__half2*)(G + (size_t)grow * 128 + c0);
      gp[0] = p0;
      gp[1] = p1;
    }
  }
}

// Generic small-M GEMM (output layer M=40), fp16 G out.
template <int M, int BM, int TM, int TN>
__global__ __launch_bounds__(256)
void gemm_scale_kernel(const float* __restrict__ X, const float* __restrict__ W,
                       const float* __restrict__ dinv, __half* __restrict__ G,
                       int nrows) {
  constexpr int BK = 32;
  constexpr int GCOL = M / TN;
  static_assert((256 / GCOL) * TM == BM, "tile shape");
  __shared__ float xs[BM][BK + 1];
  __shared__ float wsh[BK][M];

  int tid = threadIdx.x;
  int row0 = blockIdx.x * BM;
  int tx = tid % GCOL;
  int ty = tid / GCOL;
  int r0 = ty * TM;
  int c0 = tx * TN;

  float acc[TM][TN];
#pragma unroll
  for (int i = 0; i < TM; ++i)
#pragma unroll
    for (int j = 0; j < TN; ++j) acc[i][j] = 0.0f;

  for (int k0 = 0; k0 < 128; k0 += BK) {
#pragma unroll
    for (int t = tid; t < BM * (BK / 4); t += 256) {
      int r = t / (BK / 4);
      int kk = (t % (BK / 4)) * 4;
      int grow = row0 + r;
      float4 v = make_float4(0.f, 0.f, 0.f, 0.f);
      if (grow < nrows)
        v = *(const float4*)(X + (size_t)grow * 128 + k0 + kk);
      xs[r][kk] = v.x;
      xs[r][kk + 1] = v.y;
      xs[r][kk + 2] = v.z;
      xs[r][kk + 3] = v.w;
    }
#pragma unroll
    for (int t = tid; t < BK * M / 4; t += 256) {
      int k = (t * 4) / M;
      int c = (t * 4) % M;
      *(float4*)(&wsh[k][c]) = *(const float4*)(W + (size_t)(k0 + k) * M + c);
    }
    __syncthreads();
#pragma unroll 4
    for (int k = 0; k < BK; ++k) {
      float a[TM], b[TN];
#pragma unroll
      for (int i = 0; i < TM; ++i) a[i] = xs[r0 + i][k];
#pragma unroll
      for (int j = 0; j < TN; ++j) b[j] = wsh[k][c0 + j];
#pragma unroll
      for (int i = 0; i < TM; ++i)
#pragma unroll
        for (int j = 0; j < TN; ++j) acc[i][j] += a[i] * b[j];
    }
    __syncthreads();
  }
#pragma unroll
  for (int i = 0; i < TM; ++i) {
    int grow = row0 + r0 + i;
    if (grow < nrows) {
      float s = dinv[grow];
#pragma unroll
      for (int j = 0; j < TN; ++j)
        G[(size_t)grow * M + c0 + j] = __float2half_rn(s * acc[i][j]);
    }
  }
}

// out[i][:] = act( dinv[i] * (sum_{e in row i} G[col[e]][:] + G[i][:]) + b )
// G fp16 (half2/lane for M=128; lanes 0..19 half2 for M=40). fp32 accumulate.
template <int M, bool RELU>
__global__ __launch_bounds__(256)
void aggregate_kernel(const __half* __restrict__ G, const int* __restrict__ rowptr,
                      const int* __restrict__ col, const float* __restrict__ dinv,
                      const float* __restrict__ bias, float* __restrict__ out,
                      int n) {
  int wid = threadIdx.x >> 6;
  int lane = threadIdx.x & 63;
  int node = blockIdx.x * 4 + wid;
  if (node >= n) return;

  int e = rowptr[node];
  int end = rowptr[node + 1];
  float di = dinv[node];
  constexpr int H2 = M / 2;  // half2 per row
  const __half2* g2 = (const __half2*)G;

  if constexpr (M == 128) {
    float2 acc = __half22float2(g2[(size_t)node * H2 + lane]);
    for (; e + 3 < end; e += 4) {
      int s0 = col[e];
      int s1 = col[e + 1];
      int s2 = col[e + 2];
      int s3 = col[e + 3];
      float2 f0 = __half22float2(g2[(size_t)s0 * H2 + lane]);
      float2 f1 = __half22float2(g2[(size_t)s1 * H2 + lane]);
      float2 f2 = __half22float2(g2[(size_t)s2 * H2 + lane]);
      float2 f3 = __half22float2(g2[(size_t)s3 * H2 + lane]);
      acc.x += (f0.x + f1.x) + (f2.x + f3.x);
      acc.y += (f0.y + f1.y) + (f2.y + f3.y);
    }
    for (; e < end; ++e) {
      float2 f0 = __half22float2(g2[(size_t)col[e] * H2 + lane]);
      acc.x += f0.x;
      acc.y += f0.y;
    }
    float2 bb = ((const float2*)bias)[lane];
    float ox = di * acc.x + bb.x;
    float oy = di * acc.y + bb.y;
    if (RELU) {
      ox = fmaxf(ox, 0.0f);
      oy = fmaxf(oy, 0.0f);
    }
    ((float2*)out)[(size_t)node * 64 + lane] = make_float2(ox, oy);
  } else {
    if (lane < H2) {
      float2 acc = __half22float2(g2[(size_t)node * H2 + lane]);
      for (; e + 3 < end; e += 4) {
        int s0 = col[e];
        int s1 = col[e + 1];
        int s2 = col[e + 2];
        int s3 = col[e + 3];
        float2 f0 = __half22float2(g2[(size_t)s0 * H2 + lane]);
        float2 f1 = __half22float2(g2[(size_t)s1 * H2 + lane]);
        float2 f2 = __half22float2(g2[(size_t)s2 * H2 + lane]);
        float2 f3 = __half22float2(g2[(size_t)s3 * H2 + lane]);
        acc.x += (f0.x + f1.x) + (f2.x + f3.x);
        acc.y += (f0.y + f1.y) + (f2.y + f3.y);
      }
      for (; e < end; ++e) {
        float2 f0 = __half22float2(g2[(size_t)col[e] * H2 + lane]);
        acc.x += f0.x;
        acc.y += f0.y;
      }
      float2 bb = ((const float2*)bias)[lane];
      float ox = di * acc.x + bb.x;
      float oy = di * acc.y + bb.y;
      if (RELU) {
        ox = fmaxf(ox, 0.0f);
        oy = fmaxf(oy, 0.0f);
      }
      ((float2*)out)[(size_t)node * H2 + lane] = make_float2(ox, oy);
    }
  }
}

extern "C" void kernel_launch(void* const* d_in, const int* in_sizes, int n_in,
                              void* d_out, int out_size, void* d_ws, size_t ws_size,
                              hipStream_t stream) {
  const float* x = (const float*)d_in[0];
  const float* W0 = (const float*)d_in[1];
  const float* b0 = (const float*)d_in[2];
  const float* W1 = (const float*)d_in[3];
  const float* b1 = (const float*)d_in[4];
  const float* W2 = (const float*)d_in[5];
  const float* b2 = (const float*)d_in[6];
  const int* ei = (const int*)d_in[7];

  const int N = in_sizes[0] / 128;
  const int E = in_sizes[7] / 2;
  const int* src = ei;
  const int* dst = ei + E;

  char* w = (char*)d_ws;
  size_t off = 0;
  auto alloc = [&](size_t bytes) -> void* {
    void* p = w + off;
    off = (off + bytes + 255) & ~(size_t)255;
    return p;
  };
  int* cnt = (int*)alloc((size_t)N * 4);
  float* dinv = (float*)alloc((size_t)N * 4);
  int* rowptr = (int*)alloc((size_t)(N + 1) * 4);
  int* woff = (int*)alloc((size_t)N * 4);
  int* col = (int*)alloc((size_t)E * 4);
  int* blocksums = (int*)alloc(4096 * 4);
  __half* gbuf = (__half*)alloc((size_t)N * 128 * 2);   // fp16 messages
  float* hbuf = (float*)alloc((size_t)N * 128 * 4);     // fp32 activations
  (void)ws_size;

  hipMemsetAsync(cnt, 0, (size_t)N * 4, stream);

  dim3 blk(256);
  int gE = (E + 255) / 256;
  int gN = (N + 255) / 256;
  int nScanBlocks = (N + 2047) / 2048;

  deg_kernel<<<gE, blk, 0, stream>>>(dst, cnt, E);
  dinv_kernel<<<gN, blk, 0, stream>>>(cnt, dinv, N);
  scan_partial_kernel<<<nScanBlocks, blk, 0, stream>>>(cnt, blocksums, N);
  scan_blocksums_kernel<<<1, 64, 0, stream>>>(blocksums, nScanBlocks);
  scan_write_kernel<<<nScanBlocks, blk, 0, stream>>>(cnt, blocksums, rowptr, woff, N, E);

  const int P = 4;
  int chunk = (N + P - 1) / P;
  for (int p = 0; p < P; ++p) {
    int lo = p * chunk;
    int hi = min(N, lo + chunk);
    fill_phase_kernel<<<gE, blk, 0, stream>>>(src, dst, woff, col, E, lo, hi);
  }

  int gGemm128 = (N + 63) / 64;
  int gGemm40 = (N + 127) / 128;
  int gAgg = (N + 3) / 4;

  // layer 0: x -> gbuf (fp16 g0), aggregate -> hbuf (fp32 h1, relu)
  gemm128_kernel<<<gGemm128, blk, 0, stream>>>(x, W0, dinv, gbuf, N);
  aggregate_kernel<128, true><<<gAgg, blk, 0, stream>>>(gbuf, rowptr, col, dinv, b0, hbuf, N);
  // layer 1
  gemm128_kernel<<<gGemm128, blk, 0, stream>>>(hbuf, W1, dinv, gbuf, N);
  aggregate_kernel<128, true><<<gAgg, blk, 0, stream>>>(gbuf, rowptr, col, dinv, b1, hbuf, N);
  // layer 2 (M=40) -> d_out
  gemm_scale_kernel<40, 128, 4, 5><<<gGemm40, blk, 0, stream>>>(hbuf, W2, dinv, gbuf, N);
  aggregate_kernel<40, false><<<gAgg, blk, 0, stream>>>(gbuf, rowptr, col, dinv, b2,
                                                        (float*)d_out, N);
}

// Round 5
// 600.076 us; speedup vs baseline: 1.6530x; 1.0233x over previous
//
#include <hip/hip_runtime.h>
#include <hip/hip_fp16.h>

// ---------------------------------------------------------------------------
// GCN 3-layer forward. fp32 accumulate; fp16 message buffer G.
// R1: multi-block scan. R3: phase-split fill; vectorized gemm.
// R4: fp16 G halves gather bytes (agg 126->77us, FETCH 402->192MB).
// R5: lane-split aggregates (2 edges/wave-instr for M=128, 6 for M=40;
//     8B/lane loads, shuffle combine) -> more MLP, fewer load instrs.
//     gemm128 BM=128 TM=TN=8 -> 2x FMA per LDS byte.
// ---------------------------------------------------------------------------

__global__ __launch_bounds__(256)
void deg_kernel(const int* __restrict__ dst, int* __restrict__ cnt, int E) {
  int e = blockIdx.x * 256 + threadIdx.x;
  if (e < E) atomicAdd(&cnt[dst[e]], 1);
}

__global__ __launch_bounds__(256)
void dinv_kernel(const int* __restrict__ cnt, float* __restrict__ dinv, int n) {
  int i = blockIdx.x * 256 + threadIdx.x;
  if (i < n) dinv[i] = 1.0f / sqrtf((float)cnt[i] + 1.0f);
}

__global__ __launch_bounds__(256)
void scan_partial_kernel(const int* __restrict__ cnt, int* __restrict__ blocksums,
                         int n) {
  __shared__ int sm[256];
  int base = blockIdx.x * 2048 + threadIdx.x * 8;
  int s = 0;
#pragma unroll
  for (int i = 0; i < 8; ++i) {
    int idx = base + i;
    if (idx < n) s += cnt[idx];
  }
  sm[threadIdx.x] = s;
  __syncthreads();
#pragma unroll
  for (int off = 128; off > 0; off >>= 1) {
    if (threadIdx.x < off) sm[threadIdx.x] += sm[threadIdx.x + off];
    __syncthreads();
  }
  if (threadIdx.x == 0) blocksums[blockIdx.x] = sm[0];
}

__global__ void scan_blocksums_kernel(int* __restrict__ blocksums, int nb) {
  if (threadIdx.x == 0 && blockIdx.x == 0) {
    int run = 0;
    for (int i = 0; i < nb; ++i) {
      int v = blocksums[i];
      blocksums[i] = run;
      run += v;
    }
  }
}

__global__ __launch_bounds__(256)
void scan_write_kernel(const int* __restrict__ cnt, const int* __restrict__ blockoff,
                       int* __restrict__ rowptr, int* __restrict__ woff,
                       int n, int E) {
  __shared__ int sm[256];
  int t = threadIdx.x;
  int base = blockIdx.x * 2048 + t * 8;
  int v[8];
  int s = 0;
#pragma unroll
  for (int i = 0; i < 8; ++i) {
    int idx = base + i;
    v[i] = (idx < n) ? cnt[idx] : 0;
    s += v[i];
  }
  sm[t] = s;
  __syncthreads();
#pragma unroll
  for (int off = 1; off < 256; off <<= 1) {
    int u = (t >= off) ? sm[t - off] : 0;
    __syncthreads();
    sm[t] += u;
    __syncthreads();
  }
  int p = blockoff[blockIdx.x] + (t ? sm[t - 1] : 0);
#pragma unroll
  for (int i = 0; i < 8; ++i) {
    int idx = base + i;
    if (idx < n) {
      rowptr[idx] = p;
      woff[idx] = p;
      p += v[i];
    }
  }
  if (blockIdx.x == 0 && t == 0) rowptr[n] = E;
}

__global__ __launch_bounds__(256)
void fill_phase_kernel(const int* __restrict__ src, const int* __restrict__ dst,
                       int* __restrict__ woff, int* __restrict__ col, int E,
                       int lo, int hi) {
  int e = blockIdx.x * 256 + threadIdx.x;
  if (e < E) {
    int d = dst[e];
    if (d >= lo && d < hi) {
      int pos = atomicAdd(&woff[d], 1);
      col[pos] = src[e];
    }
  }
}

// G[r][c] = fp16( dinv[r] * sum_k X[r][k] * W[k][c] ). M=128, K=128.
// BM=128, BK=32, 256 threads, TM=TN=8 (64 FMA per 4x ds_read_b128).
__global__ __launch_bounds__(256)
void gemm128_kernel(const float* __restrict__ X, const float* __restrict__ W,
                    const float* __restrict__ dinv, __half* __restrict__ G,
                    int nrows) {
  constexpr int BM = 128, BK = 32, TM = 8, TN = 8;
  __shared__ float xs[BK][BM + 4];
  __shared__ float wsh[BK][128];

  int tid = threadIdx.x;
  int row0 = blockIdx.x * BM;
  int tx = tid & 15;   // 16 col groups * 8
  int ty = tid >> 4;   // 16 row groups * 8
  int r0 = ty * TM;
  int c0 = tx * TN;

  float acc[TM][TN];
#pragma unroll
  for (int i = 0; i < TM; ++i)
#pragma unroll
    for (int j = 0; j < TN; ++j) acc[i][j] = 0.0f;

  for (int k0 = 0; k0 < 128; k0 += BK) {
    // stage X (BM x BK) transposed, float4 reads along k
#pragma unroll
    for (int t = tid; t < BM * (BK / 4); t += 256) {
      int r = t >> 3;
      int kk = (t & 7) * 4;
      int grow = row0 + r;
      float4 v = make_float4(0.f, 0.f, 0.f, 0.f);
      if (grow < nrows)
        v = *(const float4*)(X + (size_t)grow * 128 + k0 + kk);
      xs[kk + 0][r] = v.x;
      xs[kk + 1][r] = v.y;
      xs[kk + 2][r] = v.z;
      xs[kk + 3][r] = v.w;
    }
    // stage W (BK x 128)
#pragma unroll
    for (int t = tid; t < BK * 32; t += 256) {
      int k = t >> 5;
      int c = (t & 31) * 4;
      *(float4*)(&wsh[k][c]) = *(const float4*)(W + (size_t)(k0 + k) * 128 + c);
    }
    __syncthreads();
#pragma unroll 4
    for (int k = 0; k < BK; ++k) {
      float4 a0 = *(const float4*)(&xs[k][r0]);
      float4 a1 = *(const float4*)(&xs[k][r0 + 4]);
      float4 b0 = *(const float4*)(&wsh[k][c0]);
      float4 b1 = *(const float4*)(&wsh[k][c0 + 4]);
      float a[TM] = {a0.x, a0.y, a0.z, a0.w, a1.x, a1.y, a1.z, a1.w};
      float bb[TN] = {b0.x, b0.y, b0.z, b0.w, b1.x, b1.y, b1.z, b1.w};
#pragma unroll
      for (int i = 0; i < TM; ++i)
#pragma unroll
        for (int j = 0; j < TN; ++j) acc[i][j] += a[i] * bb[j];
    }
    __syncthreads();
  }
#pragma unroll
  for (int i = 0; i < TM; ++i) {
    int grow = row0 + r0 + i;
    if (grow < nrows) {
      float s = dinv[grow];
      __half2* gp = (__half2*)(G + (size_t)grow * 128 + c0);
      gp[0] = __floats2half2_rn(s * acc[i][0], s * acc[i][1]);
      gp[1] = __floats2half2_rn(s * acc[i][2], s * acc[i][3]);
      gp[2] = __floats2half2_rn(s * acc[i][4], s * acc[i][5]);
      gp[3] = __floats2half2_rn(s * acc[i][6], s * acc[i][7]);
    }
  }
}

// Generic small-M GEMM (output layer M=40), fp16 G out.
template <int M, int BM, int TM, int TN>
__global__ __launch_bounds__(256)
void gemm_scale_kernel(const float* __restrict__ X, const float* __restrict__ W,
                       const float* __restrict__ dinv, __half* __restrict__ G,
                       int nrows) {
  constexpr int BK = 32;
  constexpr int GCOL = M / TN;
  static_assert((256 / GCOL) * TM == BM, "tile shape");
  __shared__ float xs[BM][BK + 1];
  __shared__ float wsh[BK][M];

  int tid = threadIdx.x;
  int row0 = blockIdx.x * BM;
  int tx = tid % GCOL;
  int ty = tid / GCOL;
  int r0 = ty * TM;
  int c0 = tx * TN;

  float acc[TM][TN];
#pragma unroll
  for (int i = 0; i < TM; ++i)
#pragma unroll
    for (int j = 0; j < TN; ++j) acc[i][j] = 0.0f;

  for (int k0 = 0; k0 < 128; k0 += BK) {
#pragma unroll
    for (int t = tid; t < BM * (BK / 4); t += 256) {
      int r = t / (BK / 4);
      int kk = (t % (BK / 4)) * 4;
      int grow = row0 + r;
      float4 v = make_float4(0.f, 0.f, 0.f, 0.f);
      if (grow < nrows)
        v = *(const float4*)(X + (size_t)grow * 128 + k0 + kk);
      xs[r][kk] = v.x;
      xs[r][kk + 1] = v.y;
      xs[r][kk + 2] = v.z;
      xs[r][kk + 3] = v.w;
    }
#pragma unroll
    for (int t = tid; t < BK * M / 4; t += 256) {
      int k = (t * 4) / M;
      int c = (t * 4) % M;
      *(float4*)(&wsh[k][c]) = *(const float4*)(W + (size_t)(k0 + k) * M + c);
    }
    __syncthreads();
#pragma unroll 4
    for (int k = 0; k < BK; ++k) {
      float a[TM], b[TN];
#pragma unroll
      for (int i = 0; i < TM; ++i) a[i] = xs[r0 + i][k];
#pragma unroll
      for (int j = 0; j < TN; ++j) b[j] = wsh[k][c0 + j];
#pragma unroll
      for (int i = 0; i < TM; ++i)
#pragma unroll
        for (int j = 0; j < TN; ++j) acc[i][j] += a[i] * b[j];
    }
    __syncthreads();
  }
#pragma unroll
  for (int i = 0; i < TM; ++i) {
    int grow = row0 + r0 + i;
    if (grow < nrows) {
      float s = dinv[grow];
#pragma unroll
      for (int j = 0; j < TN; ++j)
        G[(size_t)grow * M + c0 + j] = __float2half_rn(s * acc[i][j]);
    }
  }
}

// M=128 aggregate, lane-split: lanes 0-31 edge e, lanes 32-63 edge e+1.
// Each lane loads 8B (4 halves) of its edge's G row; fp32 accumulate;
// __shfl_xor(32) combine; lanes 0-31 store float4 (full 512B row).
template <bool RELU>
__global__ __launch_bounds__(256)
void aggregate128_kernel(const __half* __restrict__ G, const int* __restrict__ rowptr,
                         const int* __restrict__ col, const float* __restrict__ dinv,
                         const float* __restrict__ bias, float* __restrict__ out,
                         int n) {
  int wid = threadIdx.x >> 6;
  int lane = threadIdx.x & 63;
  int node = blockIdx.x * 4 + wid;
  if (node >= n) return;

  int sub = lane >> 5;      // 0 or 1
  int c = lane & 31;        // 8B chunk index within row (32 x 8B = 256B)
  const float2* g2 = (const float2*)G;  // 8B chunks; row stride = 32 chunks

  int e = rowptr[node];
  int end = rowptr[node + 1];
  float di = dinv[node];

  float ax = 0.f, ay = 0.f, az = 0.f, aw = 0.f;
  if (sub == 0) {  // self-loop term, counted once
    float2 raw = g2[(size_t)node * 32 + c];
    float2 f0 = __half22float2(*(const __half2*)&raw.x);
    float2 f1 = __half22float2(*(const __half2*)&raw.y);
    ax = f0.x; ay = f0.y; az = f1.x; aw = f1.y;
  }

  int i = e + sub;
  for (; i + 6 < end; i += 8) {  // 4 edges per half-wave, 8 per wave
    int s0 = col[i];
    int s1 = col[i + 2];
    int s2 = col[i + 4];
    int s3 = col[i + 6];
    float2 r0 = g2[(size_t)s0 * 32 + c];
    float2 r1 = g2[(size_t)s1 * 32 + c];
    float2 r2 = g2[(size_t)s2 * 32 + c];
    float2 r3 = g2[(size_t)s3 * 32 + c];
    float2 f0x = __half22float2(*(const __half2*)&r0.x);
    float2 f0y = __half22float2(*(const __half2*)&r0.y);
    float2 f1x = __half22float2(*(const __half2*)&r1.x);
    float2 f1y = __half22float2(*(const __half2*)&r1.y);
    float2 f2x = __half22float2(*(const __half2*)&r2.x);
    float2 f2y = __half22float2(*(const __half2*)&r2.y);
    float2 f3x = __half22float2(*(const __half2*)&r3.x);
    float2 f3y = __half22float2(*(const __half2*)&r3.y);
    ax += (f0x.x + f1x.x) + (f2x.x + f3x.x);
    ay += (f0x.y + f1x.y) + (f2x.y + f3x.y);
    az += (f0y.x + f1y.x) + (f2y.x + f3y.x);
    aw += (f0y.y + f1y.y) + (f2y.y + f3y.y);
  }
  for (; i < end; i += 2) {
    int s0 = col[i];
    float2 r0 = g2[(size_t)s0 * 32 + c];
    float2 f0 = __half22float2(*(const __half2*)&r0.x);
    float2 f1 = __half22float2(*(const __half2*)&r0.y);
    ax += f0.x; ay += f0.y; az += f1.x; aw += f1.y;
  }

  // combine the two half-waves
  ax += __shfl_xor(ax, 32);
  ay += __shfl_xor(ay, 32);
  az += __shfl_xor(az, 32);
  aw += __shfl_xor(aw, 32);

  if (sub == 0) {
    float4 bb = ((const float4*)bias)[c];
    float ox = di * ax + bb.x;
    float oy = di * ay + bb.y;
    float oz = di * az + bb.z;
    float ow = di * aw + bb.w;
    if (RELU) {
      ox = fmaxf(ox, 0.0f);
      oy = fmaxf(oy, 0.0f);
      oz = fmaxf(oz, 0.0f);
      ow = fmaxf(ow, 0.0f);
    }
    ((float4*)out)[(size_t)node * 32 + c] = make_float4(ox, oy, oz, ow);
  }
}

// M=40 aggregate, 6-way lane-split: sub=lane/10 handles edges e+sub, e+sub+6,...
// Each lane loads 8B (4 halves); 3-shuffle combine; lanes 0-9 store float4.
__global__ __launch_bounds__(256)
void aggregate40_kernel(const __half* __restrict__ G, const int* __restrict__ rowptr,
                        const int* __restrict__ col, const float* __restrict__ dinv,
                        const float* __restrict__ bias, float* __restrict__ out,
                        int n) {
  int wid = threadIdx.x >> 6;
  int lane = threadIdx.x & 63;
  int node = blockIdx.x * 4 + wid;
  if (node >= n) return;

  int sub = lane / 10;      // 0..5 active, 6 (lanes 60-63) idle
  int c = lane % 10;        // 8B chunk within 80B row
  const float2* g2 = (const float2*)G;  // row stride = 10 chunks

  int e = rowptr[node];
  int end = rowptr[node + 1];
  float di = dinv[node];

  float ax = 0.f, ay = 0.f, az = 0.f, aw = 0.f;
  if (sub == 0) {
    float2 raw = g2[(size_t)node * 10 + c];
    float2 f0 = __half22float2(*(const __half2*)&raw.x);
    float2 f1 = __half22float2(*(const __half2*)&raw.y);
    ax = f0.x; ay = f0.y; az = f1.x; aw = f1.y;
  }

  if (sub < 6) {
    for (int i = e + sub; i < end; i += 6) {
      int s0 = col[i];
      float2 r0 = g2[(size_t)s0 * 10 + c];
      float2 f0 = __half22float2(*(const __half2*)&r0.x);
      float2 f1 = __half22float2(*(const __half2*)&r0.y);
      ax += f0.x; ay += f0.y; az += f1.x; aw += f1.y;
    }
  }

  // tree combine: lane l += lane l+30; then lanes 0..9 += lanes c+10, c+20
  float bx = __shfl(ax, lane + 30), by = __shfl(ay, lane + 30),
        bz = __shfl(az, lane + 30), bw = __shfl(aw, lane + 30);
  ax += bx; ay += by; az += bz; aw += bw;
  float c1x = __shfl(ax, lane + 10), c1y = __shfl(ay, lane + 10),
        c1z = __shfl(az, lane + 10), c1w = __shfl(aw, lane + 10);
  float c2x = __shfl(ax, lane + 20), c2y = __shfl(ay, lane + 20),
        c2z = __shfl(az, lane + 20), c2w = __shfl(aw, lane + 20);

  if (sub == 0) {
    float sx = ax + c1x + c2x;
    float sy = ay + c1y + c2y;
    float sz = az + c1z + c2z;
    float sw = aw + c1w + c2w;
    float4 bb = ((const float4*)bias)[c];
    float4 o = make_float4(di * sx + bb.x, di * sy + bb.y, di * sz + bb.z,
                           di * sw + bb.w);
    ((float4*)out)[(size_t)node * 10 + c] = o;
  }
}

extern "C" void kernel_launch(void* const* d_in, const int* in_sizes, int n_in,
                              void* d_out, int out_size, void* d_ws, size_t ws_size,
                              hipStream_t stream) {
  const float* x = (const float*)d_in[0];
  const float* W0 = (const float*)d_in[1];
  const float* b0 = (const float*)d_in[2];
  const float* W1 = (const float*)d_in[3];
  const float* b1 = (const float*)d_in[4];
  const float* W2 = (const float*)d_in[5];
  const float* b2 = (const float*)d_in[6];
  const int* ei = (const int*)d_in[7];

  const int N = in_sizes[0] / 128;
  const int E = in_sizes[7] / 2;
  const int* src = ei;
  const int* dst = ei + E;

  char* w = (char*)d_ws;
  size_t off = 0;
  auto alloc = [&](size_t bytes) -> void* {
    void* p = w + off;
    off = (off + bytes + 255) & ~(size_t)255;
    return p;
  };
  int* cnt = (int*)alloc((size_t)N * 4);
  float* dinv = (float*)alloc((size_t)N * 4);
  int* rowptr = (int*)alloc((size_t)(N + 1) * 4);
  int* woff = (int*)alloc((size_t)N * 4);
  int* col = (int*)alloc((size_t)E * 4);
  int* blocksums = (int*)alloc(4096 * 4);
  __half* gbuf = (__half*)alloc((size_t)N * 128 * 2);
  float* hbuf = (float*)alloc((size_t)N * 128 * 4);
  (void)ws_size;

  hipMemsetAsync(cnt, 0, (size_t)N * 4, stream);

  dim3 blk(256);
  int gE = (E + 255) / 256;
  int gN = (N + 255) / 256;
  int nScanBlocks = (N + 2047) / 2048;

  deg_kernel<<<gE, blk, 0, stream>>>(dst, cnt, E);
  dinv_kernel<<<gN, blk, 0, stream>>>(cnt, dinv, N);
  scan_partial_kernel<<<nScanBlocks, blk, 0, stream>>>(cnt, blocksums, N);
  scan_blocksums_kernel<<<1, 64, 0, stream>>>(blocksums, nScanBlocks);
  scan_write_kernel<<<nScanBlocks, blk, 0, stream>>>(cnt, blocksums, rowptr, woff, N, E);

  const int P = 4;
  int chunk = (N + P - 1) / P;
  for (int p = 0; p < P; ++p) {
    int lo = p * chunk;
    int hi = min(N, lo + chunk);
    fill_phase_kernel<<<gE, blk, 0, stream>>>(src, dst, woff, col, E, lo, hi);
  }

  int gGemm128 = (N + 127) / 128;
  int gGemm40 = (N + 127) / 128;
  int gAgg = (N + 3) / 4;

  gemm128_kernel<<<gGemm128, blk, 0, stream>>>(x, W0, dinv, gbuf, N);
  aggregate128_kernel<true><<<gAgg, blk, 0, stream>>>(gbuf, rowptr, col, dinv, b0, hbuf, N);
  gemm128_kernel<<<gGemm128, blk, 0, stream>>>(hbuf, W1, dinv, gbuf, N);
  aggregate128_kernel<true><<<gAgg, blk, 0, stream>>>(gbuf, rowptr, col, dinv, b1, hbuf, N);
  gemm_scale_kernel<40, 128, 4, 5><<<gGemm40, blk, 0, stream>>>(hbuf, W2, dinv, gbuf, N);
  aggregate40_kernel<<<gAgg, blk, 0, stream>>>(gbuf, rowptr, col, dinv, b2,
                                               (float*)d_out, N);
}

// Round 6
// 588.182 us; speedup vs baseline: 1.6865x; 1.0202x over previous
//
#include <hip/hip_runtime.h>
#include <hip/hip_fp16.h>

// ---------------------------------------------------------------------------
// GCN 3-layer forward. fp32 accumulate; fp16 message buffer G.
// R1: multi-block scan. R3: phase-split fill; vectorized gemm.
// R4: fp16 G halves gather bytes (agg 126->77us, FETCH 402->192MB).
// R5: lane-split aggregates. FETCH=192MB == 8 XCD x G-size compulsory floor;
//     agg128 is at its structural gather limit.
// R6: fewer dispatches (dinv fused into scan_partial; blocksum scan folded
//     into scan_write), fill P=2, agg128 unroll-8, gemm40 vectorized.
// ---------------------------------------------------------------------------

__global__ __launch_bounds__(256)
void deg_kernel(const int* __restrict__ dst, int* __restrict__ cnt, int E) {
  int e = blockIdx.x * 256 + threadIdx.x;
  if (e < E) atomicAdd(&cnt[dst[e]], 1);
}

// Per-block partial sums of cnt (2048/block) + dinv computed on the fly.
__global__ __launch_bounds__(256)
void scan_partial_dinv_kernel(const int* __restrict__ cnt, int* __restrict__ blocksums,
                              float* __restrict__ dinv, int n) {
  __shared__ int sm[256];
  int base = blockIdx.x * 2048 + threadIdx.x * 8;
  int s = 0;
#pragma unroll
  for (int i = 0; i < 8; ++i) {
    int idx = base + i;
    if (idx < n) {
      int c = cnt[idx];
      s += c;
      dinv[idx] = 1.0f / sqrtf((float)c + 1.0f);
    }
  }
  sm[threadIdx.x] = s;
  __syncthreads();
#pragma unroll
  for (int off = 128; off > 0; off >>= 1) {
    if (threadIdx.x < off) sm[threadIdx.x] += sm[threadIdx.x + off];
    __syncthreads();
  }
  if (threadIdx.x == 0) blocksums[blockIdx.x] = sm[0];
}

// Intra-block exclusive scan + internal scan of blocksums -> rowptr, woff.
__global__ __launch_bounds__(256)
void scan_write_kernel(const int* __restrict__ cnt, const int* __restrict__ blocksums,
                       int* __restrict__ rowptr, int* __restrict__ woff,
                       int n, int E, int nb) {
  __shared__ int sm[256];
  __shared__ int bs[256];
  int t = threadIdx.x;
  if (t < nb) bs[t] = blocksums[t];
  __syncthreads();
  if (t == 0) {  // serial exclusive scan over <=256 block sums (LDS-resident)
    int run = 0;
    for (int i = 0; i < nb; ++i) {
      int v = bs[i];
      bs[i] = run;
      run += v;
    }
  }
  int base = blockIdx.x * 2048 + t * 8;
  int v[8];
  int s = 0;
#pragma unroll
  for (int i = 0; i < 8; ++i) {
    int idx = base + i;
    v[i] = (idx < n) ? cnt[idx] : 0;
    s += v[i];
  }
  sm[t] = s;
  __syncthreads();
#pragma unroll
  for (int off = 1; off < 256; off <<= 1) {
    int u = (t >= off) ? sm[t - off] : 0;
    __syncthreads();
    sm[t] += u;
    __syncthreads();
  }
  int p = bs[blockIdx.x] + (t ? sm[t - 1] : 0);
#pragma unroll
  for (int i = 0; i < 8; ++i) {
    int idx = base + i;
    if (idx < n) {
      rowptr[idx] = p;
      woff[idx] = p;
      p += v[i];
    }
  }
  if (blockIdx.x == 0 && t == 0) rowptr[n] = E;
}

// Phase-filtered counting-sort scatter; col window (~E/P*4B) stays L2-resident.
__global__ __launch_bounds__(256)
void fill_phase_kernel(const int* __restrict__ src, const int* __restrict__ dst,
                       int* __restrict__ woff, int* __restrict__ col, int E,
                       int lo, int hi) {
  int e = blockIdx.x * 256 + threadIdx.x;
  if (e < E) {
    int d = dst[e];
    if (d >= lo && d < hi) {
      int pos = atomicAdd(&woff[d], 1);
      col[pos] = src[e];
    }
  }
}

// G[r][c] = fp16( dinv[r] * sum_k X[r][k] * W[k][c] ). M=128, K=128.
__global__ __launch_bounds__(256)
void gemm128_kernel(const float* __restrict__ X, const float* __restrict__ W,
                    const float* __restrict__ dinv, __half* __restrict__ G,
                    int nrows) {
  constexpr int BM = 128, BK = 32, TM = 8, TN = 8;
  __shared__ float xs[BK][BM + 4];
  __shared__ float wsh[BK][128];

  int tid = threadIdx.x;
  int row0 = blockIdx.x * BM;
  int tx = tid & 15;
  int ty = tid >> 4;
  int r0 = ty * TM;
  int c0 = tx * TN;

  float acc[TM][TN];
#pragma unroll
  for (int i = 0; i < TM; ++i)
#pragma unroll
    for (int j = 0; j < TN; ++j) acc[i][j] = 0.0f;

  for (int k0 = 0; k0 < 128; k0 += BK) {
#pragma unroll
    for (int t = tid; t < BM * (BK / 4); t += 256) {
      int r = t >> 3;
      int kk = (t & 7) * 4;
      int grow = row0 + r;
      float4 v = make_float4(0.f, 0.f, 0.f, 0.f);
      if (grow < nrows)
        v = *(const float4*)(X + (size_t)grow * 128 + k0 + kk);
      xs[kk + 0][r] = v.x;
      xs[kk + 1][r] = v.y;
      xs[kk + 2][r] = v.z;
      xs[kk + 3][r] = v.w;
    }
#pragma unroll
    for (int t = tid; t < BK * 32; t += 256) {
      int k = t >> 5;
      int c = (t & 31) * 4;
      *(float4*)(&wsh[k][c]) = *(const float4*)(W + (size_t)(k0 + k) * 128 + c);
    }
    __syncthreads();
#pragma unroll 4
    for (int k = 0; k < BK; ++k) {
      float4 a0 = *(const float4*)(&xs[k][r0]);
      float4 a1 = *(const float4*)(&xs[k][r0 + 4]);
      float4 b0 = *(const float4*)(&wsh[k][c0]);
      float4 b1 = *(const float4*)(&wsh[k][c0 + 4]);
      float a[TM] = {a0.x, a0.y, a0.z, a0.w, a1.x, a1.y, a1.z, a1.w};
      float bb[TN] = {b0.x, b0.y, b0.z, b0.w, b1.x, b1.y, b1.z, b1.w};
#pragma unroll
      for (int i = 0; i < TM; ++i)
#pragma unroll
        for (int j = 0; j < TN; ++j) acc[i][j] += a[i] * bb[j];
    }
    __syncthreads();
  }
#pragma unroll
  for (int i = 0; i < TM; ++i) {
    int grow = row0 + r0 + i;
    if (grow < nrows) {
      float s = dinv[grow];
      __half2* gp = (__half2*)(G + (size_t)grow * 128 + c0);
      gp[0] = __floats2half2_rn(s * acc[i][0], s * acc[i][1]);
      gp[1] = __floats2half2_rn(s * acc[i][2], s * acc[i][3]);
      gp[2] = __floats2half2_rn(s * acc[i][4], s * acc[i][5]);
      gp[3] = __floats2half2_rn(s * acc[i][6], s * acc[i][7]);
    }
  }
}

// M=40 GEMM (output layer): BM=128, TM=4 (one b128 A-read), TN=5.
__global__ __launch_bounds__(256)
void gemm40_kernel(const float* __restrict__ X, const float* __restrict__ W,
                   const float* __restrict__ dinv, __half* __restrict__ G,
                   int nrows) {
  constexpr int BM = 128, BK = 32, TM = 4, TN = 5;
  __shared__ float xs[BK][BM + 4];
  __shared__ float wsh[BK][40];

  int tid = threadIdx.x;
  int row0 = blockIdx.x * BM;
  int tx = tid & 7;    // 8 col groups * 5
  int ty = tid >> 3;   // 32 row groups * 4
  int r0 = ty * TM;
  int c0 = tx * TN;

  float acc[TM][TN];
#pragma unroll
  for (int i = 0; i < TM; ++i)
#pragma unroll
    for (int j = 0; j < TN; ++j) acc[i][j] = 0.0f;

  for (int k0 = 0; k0 < 128; k0 += BK) {
#pragma unroll
    for (int t = tid; t < BM * (BK / 4); t += 256) {
      int r = t >> 3;
      int kk = (t & 7) * 4;
      int grow = row0 + r;
      float4 v = make_float4(0.f, 0.f, 0.f, 0.f);
      if (grow < nrows)
        v = *(const float4*)(X + (size_t)grow * 128 + k0 + kk);
      xs[kk + 0][r] = v.x;
      xs[kk + 1][r] = v.y;
      xs[kk + 2][r] = v.z;
      xs[kk + 3][r] = v.w;
    }
    // W tile: BK x 40 = 320 float4
#pragma unroll
    for (int t = tid; t < BK * 10; t += 256) {
      int k = t / 10;
      int c = (t % 10) * 4;
      *(float4*)(&wsh[k][c]) = *(const float4*)(W + (size_t)(k0 + k) * 40 + c);
    }
    __syncthreads();
#pragma unroll 4
    for (int k = 0; k < BK; ++k) {
      float4 a0 = *(const float4*)(&xs[k][r0]);
      float a[TM] = {a0.x, a0.y, a0.z, a0.w};
      float bb[TN];
#pragma unroll
      for (int j = 0; j < TN; ++j) bb[j] = wsh[k][c0 + j];
#pragma unroll
      for (int i = 0; i < TM; ++i)
#pragma unroll
        for (int j = 0; j < TN; ++j) acc[i][j] += a[i] * bb[j];
    }
    __syncthreads();
  }
#pragma unroll
  for (int i = 0; i < TM; ++i) {
    int grow = row0 + r0 + i;
    if (grow < nrows) {
      float s = dinv[grow];
#pragma unroll
      for (int j = 0; j < TN; ++j)
        G[(size_t)grow * 40 + c0 + j] = __float2half_rn(s * acc[i][j]);
    }
  }
}

// M=128 aggregate, lane-split (2 edges/wave-instr), unroll 8 per half-wave.
template <bool RELU>
__global__ __launch_bounds__(256)
void aggregate128_kernel(const __half* __restrict__ G, const int* __restrict__ rowptr,
                         const int* __restrict__ col, const float* __restrict__ dinv,
                         const float* __restrict__ bias, float* __restrict__ out,
                         int n) {
  int wid = threadIdx.x >> 6;
  int lane = threadIdx.x & 63;
  int node = blockIdx.x * 4 + wid;
  if (node >= n) return;

  int sub = lane >> 5;
  int c = lane & 31;
  const float2* g2 = (const float2*)G;  // 8B chunks; row stride = 32

  int e = rowptr[node];
  int end = rowptr[node + 1];
  float di = dinv[node];

  float ax = 0.f, ay = 0.f, az = 0.f, aw = 0.f;
  if (sub == 0) {
    float2 raw = g2[(size_t)node * 32 + c];
    float2 f0 = __half22float2(*(const __half2*)&raw.x);
    float2 f1 = __half22float2(*(const __half2*)&raw.y);
    ax = f0.x; ay = f0.y; az = f1.x; aw = f1.y;
  }

  int i = e + sub;
  // 8 edges per half-wave in flight (16 per wave)
  for (; i + 14 < end; i += 16) {
    float2 r[8];
#pragma unroll
    for (int u = 0; u < 8; ++u) {
      int s0 = col[i + 2 * u];
      r[u] = g2[(size_t)s0 * 32 + c];
    }
#pragma unroll
    for (int u = 0; u < 8; ++u) {
      float2 f0 = __half22float2(*(const __half2*)&r[u].x);
      float2 f1 = __half22float2(*(const __half2*)&r[u].y);
      ax += f0.x; ay += f0.y; az += f1.x; aw += f1.y;
    }
  }
  for (; i + 6 < end; i += 8) {
    float2 r[4];
#pragma unroll
    for (int u = 0; u < 4; ++u) {
      int s0 = col[i + 2 * u];
      r[u] = g2[(size_t)s0 * 32 + c];
    }
#pragma unroll
    for (int u = 0; u < 4; ++u) {
      float2 f0 = __half22float2(*(const __half2*)&r[u].x);
      float2 f1 = __half22float2(*(const __half2*)&r[u].y);
      ax += f0.x; ay += f0.y; az += f1.x; aw += f1.y;
    }
  }
  for (; i < end; i += 2) {
    int s0 = col[i];
    float2 r0 = g2[(size_t)s0 * 32 + c];
    float2 f0 = __half22float2(*(const __half2*)&r0.x);
    float2 f1 = __half22float2(*(const __half2*)&r0.y);
    ax += f0.x; ay += f0.y; az += f1.x; aw += f1.y;
  }

  ax += __shfl_xor(ax, 32);
  ay += __shfl_xor(ay, 32);
  az += __shfl_xor(az, 32);
  aw += __shfl_xor(aw, 32);

  if (sub == 0) {
    float4 bb = ((const float4*)bias)[c];
    float ox = di * ax + bb.x;
    float oy = di * ay + bb.y;
    float oz = di * az + bb.z;
    float ow = di * aw + bb.w;
    if (RELU) {
      ox = fmaxf(ox, 0.0f);
      oy = fmaxf(oy, 0.0f);
      oz = fmaxf(oz, 0.0f);
      ow = fmaxf(ow, 0.0f);
    }
    ((float4*)out)[(size_t)node * 32 + c] = make_float4(ox, oy, oz, ow);
  }
}

// M=40 aggregate, 6-way lane-split.
__global__ __launch_bounds__(256)
void aggregate40_kernel(const __half* __restrict__ G, const int* __restrict__ rowptr,
                        const int* __restrict__ col, const float* __restrict__ dinv,
                        const float* __restrict__ bias, float* __restrict__ out,
                        int n) {
  int wid = threadIdx.x >> 6;
  int lane = threadIdx.x & 63;
  int node = blockIdx.x * 4 + wid;
  if (node >= n) return;

  int sub = lane / 10;
  int c = lane % 10;
  const float2* g2 = (const float2*)G;  // row stride = 10 chunks

  int e = rowptr[node];
  int end = rowptr[node + 1];
  float di = dinv[node];

  float ax = 0.f, ay = 0.f, az = 0.f, aw = 0.f;
  if (sub == 0) {
    float2 raw = g2[(size_t)node * 10 + c];
    float2 f0 = __half22float2(*(const __half2*)&raw.x);
    float2 f1 = __half22float2(*(const __half2*)&raw.y);
    ax = f0.x; ay = f0.y; az = f1.x; aw = f1.y;
  }

  if (sub < 6) {
    int i = e + sub;
    for (; i + 11 < end; i += 12) {  // 2 edges in flight per subgroup
      int s0 = col[i];
      int s1 = col[i + 6];
      float2 r0 = g2[(size_t)s0 * 10 + c];
      float2 r1 = g2[(size_t)s1 * 10 + c];
      float2 f0 = __half22float2(*(const __half2*)&r0.x);
      float2 f1 = __half22float2(*(const __half2*)&r0.y);
      float2 f2 = __half22float2(*(const __half2*)&r1.x);
      float2 f3 = __half22float2(*(const __half2*)&r1.y);
      ax += f0.x + f2.x; ay += f0.y + f2.y;
      az += f1.x + f3.x; aw += f1.y + f3.y;
    }
    for (; i < end; i += 6) {
      int s0 = col[i];
      float2 r0 = g2[(size_t)s0 * 10 + c];
      float2 f0 = __half22float2(*(const __half2*)&r0.x);
      float2 f1 = __half22float2(*(const __half2*)&r0.y);
      ax += f0.x; ay += f0.y; az += f1.x; aw += f1.y;
    }
  }

  float bx = __shfl(ax, lane + 30), by = __shfl(ay, lane + 30),
        bz = __shfl(az, lane + 30), bw = __shfl(aw, lane + 30);
  ax += bx; ay += by; az += bz; aw += bw;
  float c1x = __shfl(ax, lane + 10), c1y = __shfl(ay, lane + 10),
        c1z = __shfl(az, lane + 10), c1w = __shfl(aw, lane + 10);
  float c2x = __shfl(ax, lane + 20), c2y = __shfl(ay, lane + 20),
        c2z = __shfl(az, lane + 20), c2w = __shfl(aw, lane + 20);

  if (sub == 0) {
    float sx = ax + c1x + c2x;
    float sy = ay + c1y + c2y;
    float sz = az + c1z + c2z;
    float sw = aw + c1w + c2w;
    float4 bb = ((const float4*)bias)[c];
    float4 o = make_float4(di * sx + bb.x, di * sy + bb.y, di * sz + bb.z,
                           di * sw + bb.w);
    ((float4*)out)[(size_t)node * 10 + c] = o;
  }
}

extern "C" void kernel_launch(void* const* d_in, const int* in_sizes, int n_in,
                              void* d_out, int out_size, void* d_ws, size_t ws_size,
                              hipStream_t stream) {
  const float* x = (const float*)d_in[0];
  const float* W0 = (const float*)d_in[1];
  const float* b0 = (const float*)d_in[2];
  const float* W1 = (const float*)d_in[3];
  const float* b1 = (const float*)d_in[4];
  const float* W2 = (const float*)d_in[5];
  const float* b2 = (const float*)d_in[6];
  const int* ei = (const int*)d_in[7];

  const int N = in_sizes[0] / 128;
  const int E = in_sizes[7] / 2;
  const int* src = ei;
  const int* dst = ei + E;

  char* w = (char*)d_ws;
  size_t off = 0;
  auto alloc = [&](size_t bytes) -> void* {
    void* p = w + off;
    off = (off + bytes + 255) & ~(size_t)255;
    return p;
  };
  int* cnt = (int*)alloc((size_t)N * 4);
  float* dinv = (float*)alloc((size_t)N * 4);
  int* rowptr = (int*)alloc((size_t)(N + 1) * 4);
  int* woff = (int*)alloc((size_t)N * 4);
  int* col = (int*)alloc((size_t)E * 4);
  int* blocksums = (int*)alloc(4096 * 4);
  __half* gbuf = (__half*)alloc((size_t)N * 128 * 2);
  float* hbuf = (float*)alloc((size_t)N * 128 * 4);
  (void)ws_size;

  hipMemsetAsync(cnt, 0, (size_t)N * 4, stream);

  dim3 blk(256);
  int gE = (E + 255) / 256;
  int nScanBlocks = (N + 2047) / 2048;  // 49 for N=100k (<=256 supported)

  deg_kernel<<<gE, blk, 0, stream>>>(dst, cnt, E);
  scan_partial_dinv_kernel<<<nScanBlocks, blk, 0, stream>>>(cnt, blocksums, dinv, N);
  scan_write_kernel<<<nScanBlocks, blk, 0, stream>>>(cnt, blocksums, rowptr, woff, N, E,
                                                     nScanBlocks);

  const int P = 2;
  int chunk = (N + P - 1) / P;
  for (int p = 0; p < P; ++p) {
    int lo = p * chunk;
    int hi = min(N, lo + chunk);
    fill_phase_kernel<<<gE, blk, 0, stream>>>(src, dst, woff, col, E, lo, hi);
  }

  int gGemm = (N + 127) / 128;
  int gAgg = (N + 3) / 4;

  gemm128_kernel<<<gGemm, blk, 0, stream>>>(x, W0, dinv, gbuf, N);
  aggregate128_kernel<true><<<gAgg, blk, 0, stream>>>(gbuf, rowptr, col, dinv, b0, hbuf, N);
  gemm128_kernel<<<gGemm, blk, 0, stream>>>(hbuf, W1, dinv, gbuf, N);
  aggregate128_kernel<true><<<gAgg, blk, 0, stream>>>(gbuf, rowptr, col, dinv, b1, hbuf, N);
  gemm40_kernel<<<gGemm, blk, 0, stream>>>(hbuf, W2, dinv, gbuf, N);
  aggregate40_kernel<<<gAgg, blk, 0, stream>>>(gbuf, rowptr, col, dinv, b2,
                                               (float*)d_out, N);
}